// Round 1
// 75.775 us; speedup vs baseline: 1.0924x; 1.0924x over previous
//
#include <hip/hip_runtime.h>
#include <math.h>

#define KTOP 200
#define NPART 32
#define BLOCK 512
#define NHIST 2048
#define CAND_CAP 512
#define WCAP 512
#define CLIST_CAP 1536   // expected qualifying keys ~625 (srank=64 * nfus/sample); 1536 = huge margin
#define SRANK_MIN 64u    // sample rank for bound E; 64 => ~17 sigma margin that exact count(<=E) >= KTOP

// d2 exactly as numpy: ((dx*dx + dy*dy) + dz*dz), no fma contraction
__device__ __forceinline__ float d2_ref(float ax, float ay, float az,
                                        float bx, float by, float bz) {
    float dx = __fsub_rn(ax, bx), dy = __fsub_rn(ay, by), dz = __fsub_rn(az, bz);
    return __fadd_rn(__fadd_rn(__fmul_rn(dx, dx), __fmul_rn(dy, dy)), __fmul_rn(dz, dz));
}

__device__ __forceinline__ unsigned key_of(const float* __restrict__ fus, int j,
                                           float vx, float vy, float vz) {
    return __float_as_uint(d2_ref(vx, vy, vz, fus[3*j], fus[3*j+1], fus[3*j+2]));
}

// shape-context bin of rel = p_j - q0, mirroring the reference f32 math
__device__ __forceinline__ int compute_bin(float rx, float ry, float rz) {
    const float TWO_PI_F = (float)6.283185307179586;
    const float PI_F     = (float)3.141592653589793;
    const float XY_W     = (float)(6.283185307179586 / 4.0);
    const float ZY_W     = (float)(3.141592653589793 / 4.0);

    float d2 = __fadd_rn(__fadd_rn(__fmul_rn(rx, rx), __fmul_rn(ry, ry)), __fmul_rn(rz, rz));
    float D  = sqrtf(__fadd_rn(d2, 1e-7f));
    float dist_bin;
    if (D >= 4.0f)      dist_bin = 1.0f;
    else if (D >= 1.0f) dist_bin = 0.0f;
    else                return -1;

    float axy = fmodf(atan2f(ry, rx) + TWO_PI_F, TWO_PI_F);
    float azy = fmodf(atan2f(ry, rz) + TWO_PI_F, PI_F);
    float xyb = floorf(__fdiv_rn(axy, XY_W));
    float zyb = floorf(__fdiv_rn(azy, ZY_W));
    if (!(xyb >= 0.0f && zyb >= 0.0f)) return -1;
    float ab  = xyb * 4.0f + zyb;
    int bin = (int)(dist_bin * 16.0f + ab);
    return bin;
}

__global__ __launch_bounds__(BLOCK, 8)
void shape_context_kernel(const float* __restrict__ veh,
                          const float* __restrict__ fus,
                          float* __restrict__ out,
                          int nfus) {
    const int b   = blockIdx.x;
    const int tid = threadIdx.x;
    const int lane = tid & 63;
    const int wid  = tid >> 6;

    __shared__ unsigned int hist[NHIST];
    __shared__ unsigned long long clist[CLIST_CAP];  // packed (key<<32 | idx), keys with bucket <= E
    __shared__ unsigned long long cand[CAND_CAP];
    __shared__ int wlist[WCAP];
    __shared__ unsigned int hist32[NPART];
    __shared__ unsigned int waveTot[BLOCK / 64];
    __shared__ unsigned int waveBase[BLOCK / 64];
    __shared__ unsigned int s_bucket, s_rem, s_bcount;
    __shared__ int s_candCount, s_wcount, s_clistCount;
    __shared__ float s_q0[3];
    __shared__ unsigned long long s_minPacked, s_lowBound;

    const float vx = veh[b * 3 + 0], vy = veh[b * 3 + 1], vz = veh[b * 3 + 2];
    const float4* fus4 = (const float4*)fus;
    const int ntrip = nfus >> 2;

    if (tid == 0) { s_minPacked = ~0ull; s_candCount = 0; s_wcount = 0; s_clistCount = 0; }
    for (int i = tid; i < NHIST; i += BLOCK) hist[i] = 0;
    if (tid < NPART) hist32[tid] = 0;
    __syncthreads();

    // parallel "find bucket where cumulative count crosses rem" over hist[NHIST]
    // leaves s_bucket = 0xFFFFFFFF if the cumulative never reaches remq
    auto find_bucket = [&](unsigned remq) {
        if (tid == 0) s_bucket = 0xFFFFFFFFu;
        const int PER = NHIST / BLOCK;  // 4
        int base = tid * PER;
        unsigned p = 0;
        #pragma unroll
        for (int i = 0; i < PER; i++) p += hist[base + i];
        unsigned incl = p;
        #pragma unroll
        for (int d = 1; d < 64; d <<= 1) {
            unsigned n = __shfl_up(incl, d, 64);
            if (lane >= d) incl += n;
        }
        if (lane == 63) waveTot[wid] = incl;
        __syncthreads();
        if (tid == 0) {
            unsigned acc = 0;
            for (int w = 0; w < BLOCK / 64; w++) { waveBase[w] = acc; acc += waveTot[w]; }
        }
        __syncthreads();
        unsigned excl = waveBase[wid] + incl - p;
        if (excl < remq && remq <= excl + p) {
            unsigned cum = excl;
            #pragma unroll
            for (int i = 0; i < PER; i++) {
                unsigned c = hist[base + i];
                if (cum + c >= remq) { s_bucket = base + i; s_rem = remq - cum; s_bcount = c; break; }
                cum += c;
            }
        }
        __syncthreads();
    };

    // ---- trip 0: full histogram of the first 4*BLOCK points (i.i.d. random sample) ----
    unsigned long long lmin = ~0ull;
    unsigned k0 = 0, k1 = 0, k2 = 0, k3 = 0;
    const bool t0v = (tid < ntrip);
    if (t0v) {
        float4 A = fus4[3 * tid], Bq = fus4[3 * tid + 1], Cq = fus4[3 * tid + 2];
        k0 = __float_as_uint(d2_ref(vx, vy, vz, A.x,  A.y,  A.z));
        k1 = __float_as_uint(d2_ref(vx, vy, vz, A.w,  Bq.x, Bq.y));
        k2 = __float_as_uint(d2_ref(vx, vy, vz, Bq.z, Bq.w, Cq.x));
        k3 = __float_as_uint(d2_ref(vx, vy, vz, Cq.y, Cq.z, Cq.w));
        atomicAdd(&hist[k0 >> 21], 1u);
        atomicAdd(&hist[k1 >> 21], 1u);
        atomicAdd(&hist[k2 >> 21], 1u);
        atomicAdd(&hist[k3 >> 21], 1u);
        unsigned jb = 4u * (unsigned)tid;
        unsigned long long p0 = ((unsigned long long)k0 << 32) | (jb + 0);
        unsigned long long p1 = ((unsigned long long)k1 << 32) | (jb + 1);
        unsigned long long p2 = ((unsigned long long)k2 << 32) | (jb + 2);
        unsigned long long p3 = ((unsigned long long)k3 << 32) | (jb + 3);
        lmin = min(min(p0, p1), min(p2, p3));
    }
    __syncthreads();

    // ---- E: conservative upper-bound bucket for the KTOP-th key, from the sample ----
    unsigned srank;
    {
        long long sample = (long long)((ntrip < BLOCK) ? ntrip : BLOCK) * 4;
        if (sample >= (long long)nfus) {
            srank = KTOP;  // sample is the whole population -> exact
        } else {
            unsigned s2 = (unsigned)(((long long)3 * KTOP * sample + nfus - 1) / nfus);
            srank = (s2 < SRANK_MIN) ? SRANK_MIN : s2;
        }
    }
    find_bucket(srank);
    const unsigned E = (s_bucket < NHIST) ? s_bucket : (NHIST - 1);  // unset -> no filtering

    // trip-0 keys: already in hist; push qualifiers into clist
    if (t0v) {
        unsigned jb = 4u * (unsigned)tid;
        if ((k0 >> 21) <= E) { int pos = atomicAdd(&s_clistCount, 1); if (pos < CLIST_CAP) clist[pos] = ((unsigned long long)k0 << 32) | (jb + 0); }
        if ((k1 >> 21) <= E) { int pos = atomicAdd(&s_clistCount, 1); if (pos < CLIST_CAP) clist[pos] = ((unsigned long long)k1 << 32) | (jb + 1); }
        if ((k2 >> 21) <= E) { int pos = atomicAdd(&s_clistCount, 1); if (pos < CLIST_CAP) clist[pos] = ((unsigned long long)k2 << 32) | (jb + 2); }
        if ((k3 >> 21) <= E) { int pos = atomicAdd(&s_clistCount, 1); if (pos < CLIST_CAP) clist[pos] = ((unsigned long long)k3 << 32) | (jb + 3); }
    }

    // ---- main stream: one compare per key; only ~3% (bucket <= E) touch LDS ----
    for (int m = BLOCK + tid; m < ntrip; m += BLOCK) {
        float4 A = fus4[3 * m], Bq = fus4[3 * m + 1], Cq = fus4[3 * m + 2];
        unsigned q0k = __float_as_uint(d2_ref(vx, vy, vz, A.x,  A.y,  A.z));
        unsigned q1k = __float_as_uint(d2_ref(vx, vy, vz, A.w,  Bq.x, Bq.y));
        unsigned q2k = __float_as_uint(d2_ref(vx, vy, vz, Bq.z, Bq.w, Cq.x));
        unsigned q3k = __float_as_uint(d2_ref(vx, vy, vz, Cq.y, Cq.z, Cq.w));
        unsigned jb = 4u * (unsigned)m;
        unsigned long long p0 = ((unsigned long long)q0k << 32) | (jb + 0);
        unsigned long long p1 = ((unsigned long long)q1k << 32) | (jb + 1);
        unsigned long long p2 = ((unsigned long long)q2k << 32) | (jb + 2);
        unsigned long long p3 = ((unsigned long long)q3k << 32) | (jb + 3);
        lmin = min(lmin, min(min(p0, p1), min(p2, p3)));
        if ((q0k >> 21) <= E) { atomicAdd(&hist[q0k >> 21], 1u); int pos = atomicAdd(&s_clistCount, 1); if (pos < CLIST_CAP) clist[pos] = p0; }
        if ((q1k >> 21) <= E) { atomicAdd(&hist[q1k >> 21], 1u); int pos = atomicAdd(&s_clistCount, 1); if (pos < CLIST_CAP) clist[pos] = p1; }
        if ((q2k >> 21) <= E) { atomicAdd(&hist[q2k >> 21], 1u); int pos = atomicAdd(&s_clistCount, 1); if (pos < CLIST_CAP) clist[pos] = p2; }
        if ((q3k >> 21) <= E) { atomicAdd(&hist[q3k >> 21], 1u); int pos = atomicAdd(&s_clistCount, 1); if (pos < CLIST_CAP) clist[pos] = p3; }
    }
    // tail (nfus % 4)
    for (int j = (nfus & ~3) + tid; j < nfus; j += BLOCK) {
        unsigned k = key_of(fus, j, vx, vy, vz);
        lmin = min(lmin, ((unsigned long long)k << 32) | (unsigned)j);
        if ((k >> 21) <= E) { atomicAdd(&hist[k >> 21], 1u); int pos = atomicAdd(&s_clistCount, 1); if (pos < CLIST_CAP) clist[pos] = ((unsigned long long)k << 32) | (unsigned)j; }
    }

    #pragma unroll
    for (int d = 32; d > 0; d >>= 1) {
        unsigned long long o = __shfl_xor(lmin, d, 64);
        lmin = (o < lmin) ? o : lmin;
    }
    if (lane == 0) atomicMin(&s_minPacked, lmin);
    __syncthreads();

    // hist is now EXACT on [0, E]; garbage (sample-only) above E. A crossing at T <= E is exact.
    find_bucket(KTOP);
    unsigned T = s_bucket;
    unsigned rem = s_rem;
    unsigned bcount = s_bcount;
    int shift = 21;
    const bool fastOK = (s_clistCount <= CLIST_CAP) && (T <= E);

    if (tid == 0) {
        int idx0 = (int)(s_minPacked & 0xFFFFFFFFull);
        s_q0[0] = fus[idx0 * 3]; s_q0[1] = fus[idx0 * 3 + 1]; s_q0[2] = fus[idx0 * 3 + 2];
    }
    __syncthreads();
    const float q0x = s_q0[0], q0y = s_q0[1], q0z = s_q0[2];

    if (!fastOK) {
        // rare: bound E failed or clist overflowed -> rebuild the full exact histogram
        for (int i = tid; i < NHIST; i += BLOCK) hist[i] = 0;
        __syncthreads();
        for (int j = tid; j < nfus; j += BLOCK) {
            unsigned k = key_of(fus, j, vx, vy, vz);
            atomicAdd(&hist[k >> 21], 1u);
        }
        __syncthreads();
        find_bucket(KTOP);
        T = s_bucket; rem = s_rem; bcount = s_bcount;
    }

    // ---- rare: refine threshold bucket if too many candidates (reload-based) ----
    while (bcount > CAND_CAP && shift > 0) {
        int newshift = (shift > 11) ? (shift - 11) : 0;
        unsigned digmask = (1u << (shift - newshift)) - 1;
        for (int i = tid; i < NHIST; i += BLOCK) hist[i] = 0;
        __syncthreads();
        for (int j = tid; j < nfus; j += BLOCK) {
            unsigned k = key_of(fus, j, vx, vy, vz);
            if ((k >> shift) == T) atomicAdd(&hist[(k >> newshift) & digmask], 1u);
        }
        __syncthreads();
        find_bucket(rem);
        T = (T << (shift - newshift)) | s_bucket;
        rem = s_rem;
        bcount = s_bcount;
        shift = newshift;
    }

    // ---- scan B: winners -> wlist, boundary bucket -> cand ----
    if (fastOK && shift == 21) {
        // walk the compact candidate list (exact packed keys, ~625 entries)
        const int cn = s_clistCount;
        for (int i = tid; i < cn; i += BLOCK) {
            unsigned long long p = clist[i];
            unsigned hi = (unsigned)(p >> 53);   // == key >> 21
            if (hi < T) {
                int pos = atomicAdd(&s_wcount, 1);
                if (pos < WCAP) wlist[pos] = (int)(p & 0xFFFFFFFFull);
            } else if (hi == T) {
                int pos = atomicAdd(&s_candCount, 1);
                if (pos < CAND_CAP) cand[pos] = p;
            }
        }
    } else {
        for (int j = tid; j < nfus; j += BLOCK) {
            unsigned k = key_of(fus, j, vx, vy, vz);
            unsigned hi = k >> shift;
            if (hi < T) { int pos = atomicAdd(&s_wcount, 1); if (pos < WCAP) wlist[pos] = j; }
            else if (hi == T) { int pos = atomicAdd(&s_candCount, 1); if (pos < CAND_CAP) cand[pos] = ((unsigned long long)k << 32) | (unsigned)j; }
        }
    }
    __syncthreads();

    const int cnt = s_candCount;
    if (cnt <= CAND_CAP) {
        // exact stable ranking among boundary candidates by (key, idx); qualifiers join wlist
        for (int i = tid; i < cnt; i += BLOCK) {
            unsigned long long me = cand[i];
            int rank = 0;
            for (int k2 = 0; k2 < cnt; k2++) rank += (cand[k2] < me) ? 1 : 0;
            if (rank < (int)rem) {
                int pos = atomicAdd(&s_wcount, 1);
                if (pos < WCAP) wlist[pos] = (int)(me & 0xFFFFFFFFull);
            }
        }
    }
    __syncthreads();

    // ---- compact winner processing: ~one compute_bin per thread ----
    {
        int wc = s_wcount; if (wc > WCAP) wc = WCAP;
        for (int i = tid; i < wc; i += BLOCK) {
            int j = wlist[i];
            float fx = fus[3 * j], fy = fus[3 * j + 1], fz = fus[3 * j + 2];
            int bin = compute_bin(__fsub_rn(fx, q0x), __fsub_rn(fy, q0y), __fsub_rn(fz, q0z));
            if (bin >= 0 && bin < NPART) atomicAdd(&hist32[bin], 1u);
        }
    }
    __syncthreads();

    if (cnt > CAND_CAP) {
        // pathological fallback: serial extraction of `rem` smallest packed (key,idx) in bucket T
        if (tid == 0) s_lowBound = 0;
        __syncthreads();
        for (unsigned itx = 0; itx < rem; ++itx) {
            if (tid == 0) s_minPacked = ~0ull;
            __syncthreads();
            unsigned long long lowB = s_lowBound;
            unsigned long long lm = ~0ull;
            for (int j = tid; j < nfus; j += BLOCK) {
                unsigned k = key_of(fus, j, vx, vy, vz);
                if ((k >> shift) == T) {
                    unsigned long long p = ((unsigned long long)k << 32) | (unsigned)j;
                    if (p >= lowB && p < lm) lm = p;
                }
            }
            #pragma unroll
            for (int d = 32; d > 0; d >>= 1) {
                unsigned long long o = __shfl_xor(lm, d, 64);
                lm = (o < lm) ? o : lm;
            }
            if (lane == 0) atomicMin(&s_minPacked, lm);
            __syncthreads();
            if (tid == 0) {
                int jm = (int)(s_minPacked & 0xFFFFFFFFull);
                float fx = fus[jm * 3], fy = fus[jm * 3 + 1], fz = fus[jm * 3 + 2];
                int bin = compute_bin(__fsub_rn(fx, q0x), __fsub_rn(fy, q0y), __fsub_rn(fz, q0z));
                if (bin >= 0 && bin < NPART) hist32[bin] += 1u;
                s_lowBound = s_minPacked + 1;
            }
            __syncthreads();
        }
    }

    // ---- epilogue (32 lanes of wave 0): counts+1 -> L2-normalize*4 -> softmax ----
    if (tid < NPART) {
        float c = (float)hist32[tid] + 1.0f;
        float ss = __fmul_rn(c, c);
        #pragma unroll
        for (int d = 16; d > 0; d >>= 1) ss += __shfl_xor(ss, d, 64);
        float v = __fmul_rn(__fdiv_rn(c, sqrtf(ss)), 4.0f);
        float mx = v;
        #pragma unroll
        for (int d = 16; d > 0; d >>= 1) mx = fmaxf(mx, __shfl_xor(mx, d, 64));
        float e = expf(v - mx);
        float sum = e;
        #pragma unroll
        for (int d = 16; d > 0; d >>= 1) sum += __shfl_xor(sum, d, 64);
        out[b * NPART + tid] = __fdiv_rn(e, sum);
    }
}

extern "C" void kernel_launch(void* const* d_in, const int* in_sizes, int n_in,
                              void* d_out, int out_size, void* d_ws, size_t ws_size,
                              hipStream_t stream) {
    const float* veh = (const float*)d_in[0];   // (1024, 3)
    const float* fus = (const float*)d_in[1];   // (20000, 3)
    float* out = (float*)d_out;                 // (1024, 32)
    int nveh = in_sizes[0] / 3;
    int nfus = in_sizes[1] / 3;
    shape_context_kernel<<<nveh, BLOCK, 0, stream>>>(veh, fus, out, nfus);
}